// Round 16
// baseline (943.582 us; speedup 1.0000x reference)
//
#include <hip/hip_runtime.h>
#include <stdint.h>

typedef unsigned short u16;
typedef uint32_t u32;
typedef unsigned long long u64;
typedef short bf16x8 __attribute__((ext_vector_type(8)));
typedef float f32x4 __attribute__((ext_vector_type(4)));
typedef float f32x16 __attribute__((ext_vector_type(16)));

#define MFMA16 __builtin_amdgcn_mfma_f32_16x16x32_bf16
#define MFMA32 __builtin_amdgcn_mfma_f32_32x32x16_bf16
#define L2E 1.44269504088896340736f

static __device__ __forceinline__ u16 f2bf(float f) {
  union { float f; u32 u; } v; v.f = f;
  u32 r = v.u + 0x7FFFu + ((v.u >> 16) & 1u);
  return (u16)(r >> 16);
}

// hardware packed f32x2 -> bf16x2 (RNE); no builtin on gfx950 (guide m240)
static __device__ __forceinline__ u32 cvtpk(float lo, float hi) {
  u32 r;
  asm("v_cvt_pk_bf16_f32 %0, %1, %2" : "=v"(r) : "v"(lo), "v"(hi));
  return r;
}

static __device__ __forceinline__ void glds16(const u16* g, u16* l) {
  __builtin_amdgcn_global_load_lds((const __attribute__((address_space(1))) void*)g,
                                   (__attribute__((address_space(3))) void*)l, 16, 0, 0);
}

// -------- convert 3 fp32 tensors (same size) to bf16, 8 elems/thread --------
__global__ __launch_bounds__(256) void cvt3_kernel(
    const float* __restrict__ s0, const float* __restrict__ s1, const float* __restrict__ s2,
    u16* __restrict__ d0, u16* __restrict__ d1, u16* __restrict__ d2) {
  const float* s = (blockIdx.z == 0) ? s0 : (blockIdx.z == 1) ? s1 : s2;
  u16* d = (blockIdx.z == 0) ? d0 : (blockIdx.z == 1) ? d1 : d2;
  size_t i = ((size_t)blockIdx.x * 256 + threadIdx.x) * 8;
  float4 a = *(const float4*)(s + i);
  float4 c = *(const float4*)(s + i + 4);
  bf16x8 o;
  o[0] = (short)f2bf(a.x); o[1] = (short)f2bf(a.y);
  o[2] = (short)f2bf(a.z); o[3] = (short)f2bf(a.w);
  o[4] = (short)f2bf(c.x); o[5] = (short)f2bf(c.y);
  o[6] = (short)f2bf(c.z); o[7] = (short)f2bf(c.w);
  *(bf16x8*)(d + i) = o;
}

// -------- transpose-convert the 4 weight matrices: Wt[n][k] = bf16(W[k][n]) --------
__global__ __launch_bounds__(256) void wtrans_kernel(
    const float* __restrict__ w0, const float* __restrict__ w1,
    const float* __restrict__ w2, const float* __restrict__ w3,
    u16* __restrict__ t0, u16* __restrict__ t1, u16* __restrict__ t2, u16* __restrict__ t3) {
  const float* w = (blockIdx.z == 0) ? w0 : (blockIdx.z == 1) ? w1 : (blockIdx.z == 2) ? w2 : w3;
  u16* t = (blockIdx.z == 0) ? t0 : (blockIdx.z == 1) ? t1 : (blockIdx.z == 2) ? t2 : t3;
  __shared__ float tile[64][65];
  const int bx = blockIdx.x, by = blockIdx.y;
#pragma unroll
  for (int i = 0; i < 16; ++i) {
    int idx = i * 256 + threadIdx.x;
    int r = idx >> 6, c = idx & 63;
    tile[r][c] = w[(size_t)(by * 64 + r) * 1024 + bx * 64 + c];
  }
  __syncthreads();
#pragma unroll
  for (int i = 0; i < 16; ++i) {
    int idx = i * 256 + threadIdx.x;
    int r = idx >> 6, c = idx & 63;
    t[(size_t)(bx * 64 + r) * 1024 + by * 64 + c] = f2bf(tile[c][r]);
  }
}

// -------- pack int32 mask (0/1) into bits: word w covers k = 32w..32w+31 --------
__global__ __launch_bounds__(256) void packmask_kernel(const int* __restrict__ m,
                                                       u32* __restrict__ pmo) {
  const size_t i = (size_t)blockIdx.x * 256 + threadIdx.x;
  const int lane = threadIdx.x & 63;
  unsigned long long b = __ballot(m[i] != 0);
  if (lane == 0) pmo[i >> 5] = (u32)b;
  else if (lane == 32) pmo[i >> 5] = (u32)(b >> 32);
}

// -------- bf16 GEMM: BM=256 BN=128 BK=64, 512 thr (8 waves 4Mx2N), 3-buffer --------
// counted-vmcnt (T4), XOR-swizzled LDS (T2), setprio (T5), T1 XCD block swizzle,
// phase-split K-step (T3): unchanged from round 14 (proven 29 -> 24.5 us).
template <int OM>
__global__ __launch_bounds__(512, 2) void gemm_kernel(
    const u16* __restrict__ A, const u16* __restrict__ Bt, const float* __restrict__ bias,
    void* __restrict__ Cout, float oscale) {
  constexpr int K = 1024, N = 1024;
  constexpr int NT = K / 64;  // 16 K-tiles
  __shared__ u16 As[3][256 * 64];  // 96 KB
  __shared__ u16 Bs[3][128 * 64];  // 48 KB
  const int tid = threadIdx.x;
  const int lane = tid & 63;
  const int wid = tid >> 6;       // 0..7
  const int l15 = lane & 15;
  const int lg = lane >> 4;
  const int orig = blockIdx.x;                     // 0..255
  const int wgid = (orig & 7) * 32 + (orig >> 3);  // XCD-contiguous remap
  const int row0 = (wgid >> 3) * 256;              // 32 row-panels
  const int col0 = (wgid & 7) * 128;               // 8 col-blocks
  const int wr = wid >> 1, wc = wid & 1;  // 4M x 2N wave grid
  const int swf = (l15 & 7) << 3;         // read-side XOR swizzle (u16 units)
  const f32x4 fzero = {0.f, 0.f, 0.f, 0.f};

  f32x4 acc[4][4];
#pragma unroll
  for (int m = 0; m < 4; ++m)
#pragma unroll
    for (int n = 0; n < 4; ++n) acc[m][n] = fzero;

  // A-loads i in [a0,a1), B-loads i in [b0,b1)
#define GSTAGE_PART(buf, k0, a0, a1, b0, b1)                                   \
  do {                                                                         \
    _Pragma("unroll") for (int i = (a0); i < (a1); ++i) {                      \
      int e = (i * 512 + tid) * 8;                                             \
      int r = e >> 6, c = e & 63;                                              \
      int cs = c ^ ((r & 7) << 3);                                             \
      glds16(A + (size_t)(row0 + r) * K + (k0) + cs, &As[buf][e]);             \
    }                                                                          \
    _Pragma("unroll") for (int i = (b0); i < (b1); ++i) {                      \
      int e = (i * 512 + tid) * 8;                                             \
      int r = e >> 6, c = e & 63;                                              \
      int cs = c ^ ((r & 7) << 3);                                             \
      glds16(Bt + (size_t)(col0 + r) * K + (k0) + cs, &Bs[buf][e]);            \
    }                                                                          \
  } while (0)

  GSTAGE_PART(0, 0, 0, 4, 0, 2);
  GSTAGE_PART(1, 64, 0, 4, 0, 2);
  asm volatile("s_waitcnt vmcnt(6)" ::: "memory");  // tile 0 landed
  __builtin_amdgcn_s_barrier();
  __builtin_amdgcn_sched_barrier(0);

  for (int t = 0; t < NT; ++t) {
    const int buf = t % 3;
    const int buf2 = (t + 2) % 3;
    const int k2 = (t + 2) * 64;
    const bool stg = (t + 2 < NT);

    // ---- phase 0: frags(ks=0) + first staging half ----
    {
      const int koff = 0 * 32 + lg * 8;
      bf16x8 af[4], bfr[4];
#pragma unroll
      for (int m = 0; m < 4; ++m)
        af[m] = *(const bf16x8*)(&As[buf][(wr * 64 + m * 16 + l15) * 64 + (koff ^ swf)]);
#pragma unroll
      for (int n = 0; n < 4; ++n)
        bfr[n] = *(const bf16x8*)(&Bs[buf][(wc * 64 + n * 16 + l15) * 64 + (koff ^ swf)]);
      if (stg) GSTAGE_PART(buf2, k2, 0, 2, 0, 1);
      __builtin_amdgcn_sched_barrier(0);
      __builtin_amdgcn_s_barrier();
      asm volatile("s_waitcnt lgkmcnt(0)" ::: "memory");
      __builtin_amdgcn_sched_barrier(0);
      __builtin_amdgcn_s_setprio(1);
#pragma unroll
      for (int m = 0; m < 4; ++m)
#pragma unroll
        for (int n = 0; n < 4; ++n)
          acc[m][n] = MFMA16(af[m], bfr[n], acc[m][n], 0, 0, 0);
      __builtin_amdgcn_s_setprio(0);
      __builtin_amdgcn_sched_barrier(0);
      __builtin_amdgcn_s_barrier();
    }

    // ---- phase 1: frags(ks=1) + second staging half ----
    {
      const int koff = 1 * 32 + lg * 8;
      bf16x8 af[4], bfr[4];
#pragma unroll
      for (int m = 0; m < 4; ++m)
        af[m] = *(const bf16x8*)(&As[buf][(wr * 64 + m * 16 + l15) * 64 + (koff ^ swf)]);
#pragma unroll
      for (int n = 0; n < 4; ++n)
        bfr[n] = *(const bf16x8*)(&Bs[buf][(wc * 64 + n * 16 + l15) * 64 + (koff ^ swf)]);
      if (stg) GSTAGE_PART(buf2, k2, 2, 4, 1, 2);
      __builtin_amdgcn_sched_barrier(0);
      __builtin_amdgcn_s_barrier();
      asm volatile("s_waitcnt lgkmcnt(0)" ::: "memory");
      __builtin_amdgcn_sched_barrier(0);
      __builtin_amdgcn_s_setprio(1);
#pragma unroll
      for (int m = 0; m < 4; ++m)
#pragma unroll
        for (int n = 0; n < 4; ++n)
          acc[m][n] = MFMA16(af[m], bfr[n], acc[m][n], 0, 0, 0);
      __builtin_amdgcn_s_setprio(0);
    }

    if (t + 1 < NT) {
      if (t + 2 < NT)
        asm volatile("s_waitcnt vmcnt(6)" ::: "memory");  // tile t+1 landed, t+2 in flight
      else
        asm volatile("s_waitcnt vmcnt(0)" ::: "memory");  // tail: last tile landed
      __builtin_amdgcn_s_barrier();
      __builtin_amdgcn_sched_barrier(0);
    }
  }
#undef GSTAGE_PART

#pragma unroll
  for (int n = 0; n < 4; ++n) {
    const int col = col0 + wc * 64 + n * 16 + l15;
    const float bv = bias[col];
#pragma unroll
    for (int m = 0; m < 4; ++m) {
#pragma unroll
      for (int r = 0; r < 4; ++r) {
        const int row = row0 + wr * 64 + m * 16 + lg * 4 + r;
        const float v = (acc[m][n][r] + bv) * oscale;
        if constexpr (OM == 0) {
          ((u16*)Cout)[(size_t)row * N + col] = f2bf(v);
        } else if constexpr (OM == 1) {
          ((float*)Cout)[(size_t)row * N + col] = v;
        } else {
          const int b_ = row >> 11, s_ = row & 2047, h_ = col >> 6, d_ = col & 63;
          ((u16*)Cout)[(size_t)((b_ * 16 + h_) * 64 + d_) * 2048 + s_] = f2bf(v);
        }
      }
    }
  }
}

// -------- flash attention: 32x32x16 MFMA, in-register P via permlane32_swap --------
// Round-14 2-buffer skeleton (proven best; round-15's 3-buffer cost occupancy and
// regressed) rescaled to 512 THREADS / 8 WAVES per block: same 32 KB K/V double-
// buffer now shared by 256 q-rows -> staging traffic and FETCH halve, and
// occupancy doubles (4 blocks x 8 waves = 32 waves/CU). __launch_bounds__(512,8)
// caps VGPR at 64 (uses 60). STAGE re-derived for 512 threads: per-lane global
// source; wave-uniform LDS dest wid*512 (lane x 16B implicit — rule #21).
__global__ __launch_bounds__(512, 8) void attn_kernel(
    const u16* __restrict__ Qb, const u16* __restrict__ Kb, const u16* __restrict__ Vt,
    const u32* __restrict__ pm, u16* __restrict__ Oa) {
  __shared__ u16 Ks[2][64 * 64];
  __shared__ u16 Vs[2][64 * 64];
  __shared__ uint4 mlut[16];  // 4 keep-bits -> 4 u32 AND-words
  const int tid = threadIdx.x;   // 0..511
  const int lane = tid & 63;
  const int wid = tid >> 6;      // 0..7
  const int c31 = lane & 31;
  const int hi = lane >> 5;
  const int orig = blockIdx.x;                     // 0..511
  const int wgid = (orig & 7) * 64 + (orig >> 3);  // XCD-contiguous remap (512 = 8x64)
  const int qt = wgid & 7;          // 8 q-tiles of 256
  const int hh = (wgid >> 3) & 15;  // 16 heads
  const int bb = wgid >> 7;         // 4 batches
  const int qbase = qt * 256 + wid * 32;
  const int sw = (lane & 7) << 3;  // LDS read-side XOR swizzle (u16 units)

  if (tid < 16)
    mlut[tid] = make_uint4((u32) - (int)(tid & 1), (u32) - (int)((tid >> 1) & 1),
                           (u32) - (int)((tid >> 2) & 1), (u32) - (int)((tid >> 3) & 1));

  // Q B-fragments: col = q = qbase + c31, k = hi*8 + e, d = ds*16 + k
  const size_t qrow = (size_t)(bb * 2048 + qbase + c31);
  bf16x8 qf[4];
#pragma unroll
  for (int ds = 0; ds < 4; ++ds)
    qf[ds] = *(const bf16x8*)(Qb + qrow * 1024 + hh * 64 + ds * 16 + hi * 8);

  float lrun = 0.f;
  f32x16 oacc[2];
#pragma unroll
  for (int dn = 0; dn < 2; ++dn)
#pragma unroll
    for (int r = 0; r < 16; ++r) oacc[dn][r] = 0.f;

  const size_t kgbase = (size_t)(bb * 2048) * 1024 + hh * 64;
  const size_t vgbase = (size_t)((bb * 16 + hh) * 64) * 2048;

  // 512 threads cover one 64x64 tile per buffer in ONE pass (tid*8 u16 each).
#define STAGE(buf, kbase)                                                              \
  do {                                                                                 \
    int r = (tid * 8) >> 6, c = (tid * 8) & 63;                                        \
    int cs = c ^ ((r & 7) << 3);                                                       \
    glds16(Kb + kgbase + (size_t)((kbase) + r) * 1024 + cs, &Ks[buf][wid * 512]);      \
    glds16(Vt + vgbase + (size_t)r * 2048 + (kbase) + cs, &Vs[buf][wid * 512]);        \
  } while (0)

  STAGE(0, 0);
  __syncthreads();  // buf0 staged (vmcnt0 drained), mlut visible

  int cur = 0;
  for (int kt = 0; kt < 32; ++kt) {
    if (kt < 31) STAGE(cur ^ 1, (kt + 1) * 64);

    // both 32-key mask words for this tile (row = this lane's q)
    const u64 mw = *(const u64*)(pm + qrow * 64 + kt * 2);
    float ps = 0.f;

#pragma unroll
    for (int kb = 0; kb < 2; ++kb) {
      // QK^T: St[key = kb*32 + (r&3)+8*(r>>2)+4*hi][q = c31]
      f32x16 sacc;
#pragma unroll
      for (int r = 0; r < 16; ++r) sacc[r] = 0.f;
#pragma unroll
      for (int ds = 0; ds < 4; ++ds) {
        bf16x8 kf = *(const bf16x8*)(&Ks[cur][(kb * 32 + c31) * 64 + ((ds * 16 + hi * 8) ^ sw)]);
        sacc = MFMA32(kf, qf[ds], sacc, 0, 0, 0);
      }

      // exp + LUT mask + pack to bf16 pairs (in registers)
      const u32 mwk = (u32)(mw >> (kb * 32));
      u32 Ap[4], Bp[4];
#pragma unroll
      for (int q2 = 0; q2 < 4; ++q2) {
        const u32 kb4 = (mwk >> (q2 * 8 + hi * 4)) & 0xFu;
        const uint4 mm = mlut[kb4];
        const float p0 = __builtin_amdgcn_exp2f(sacc[4 * q2 + 0]);
        const float p1 = __builtin_amdgcn_exp2f(sacc[4 * q2 + 1]);
        const float p2 = __builtin_amdgcn_exp2f(sacc[4 * q2 + 2]);
        const float p3 = __builtin_amdgcn_exp2f(sacc[4 * q2 + 3]);
        const float f0 = __uint_as_float(__float_as_uint(p0) & mm.x);
        const float f1 = __uint_as_float(__float_as_uint(p1) & mm.y);
        const float f2 = __uint_as_float(__float_as_uint(p2) & mm.z);
        const float f3 = __uint_as_float(__float_as_uint(p3) & mm.w);
        ps += (f0 + f1) + (f2 + f3);
        Ap[q2] = cvtpk(f0, f1);
        Bp[q2] = cvtpk(f2, f3);
      }

      // redistribute across hi-halves: B-frag regs r0,r2 from A-pair swap, r1,r3 from B-pair
      asm("v_permlane32_swap_b32 %0, %1" : "+v"(Ap[0]), "+v"(Ap[1]));
      asm("v_permlane32_swap_b32 %0, %1" : "+v"(Bp[0]), "+v"(Bp[1]));
      asm("v_permlane32_swap_b32 %0, %1" : "+v"(Ap[2]), "+v"(Ap[3]));
      asm("v_permlane32_swap_b32 %0, %1" : "+v"(Bp[2]), "+v"(Bp[3]));

      // PV: O^T[d][q] += V^T[d][key] * P[key][q], 2 key-steps of 16 per kb
#pragma unroll
      for (int t = 0; t < 2; ++t) {
        uint4 fr;
        fr.x = Ap[2 * t]; fr.y = Bp[2 * t]; fr.z = Ap[2 * t + 1]; fr.w = Bp[2 * t + 1];
        const bf16x8 pf = *(const bf16x8*)&fr;
        const int koff = (kb * 2 + t) * 16 + hi * 8;
#pragma unroll
        for (int dn = 0; dn < 2; ++dn) {
          bf16x8 vf = *(const bf16x8*)(&Vs[cur][(dn * 32 + c31) * 64 + (koff ^ sw)]);
          oacc[dn] = MFMA32(vf, pf, oacc[dn], 0, 0, 0);
        }
      }
    }

    ps += __shfl_xor(ps, 32);
    lrun += ps;

    __syncthreads();  // vmcnt(0): next tile staged; lgkmcnt(0): buf[cur] reads done
    cur ^= 1;
  }
#undef STAGE

  // epilogue: O[q][d], lane owns q = qbase + c31; d = dn*32 + q2*8 + hi*4 + {0..3}
  const float inv = 1.0f / lrun;
  u16* orow = Oa + qrow * 1024 + hh * 64;
#pragma unroll
  for (int dn = 0; dn < 2; ++dn) {
#pragma unroll
    for (int q2 = 0; q2 < 4; ++q2) {
      uint2 w;
      w.x = cvtpk(oacc[dn][4 * q2 + 0] * inv, oacc[dn][4 * q2 + 1] * inv);
      w.y = cvtpk(oacc[dn][4 * q2 + 2] * inv, oacc[dn][4 * q2 + 3] * inv);
      *(uint2*)(orow + dn * 32 + q2 * 8 + hi * 4) = w;
    }
  }
}

extern "C" void kernel_launch(void* const* d_in, const int* in_sizes, int n_in,
                              void* d_out, int out_size, void* d_ws, size_t ws_size,
                              hipStream_t stream) {
  const float* q = (const float*)d_in[0];
  const float* k = (const float*)d_in[1];
  const float* v = (const float*)d_in[2];
  const int* mask = (const int*)d_in[3];
  const float* Wq = (const float*)d_in[4]; const float* bq = (const float*)d_in[5];
  const float* Wk = (const float*)d_in[6]; const float* bk = (const float*)d_in[7];
  const float* Wv = (const float*)d_in[8]; const float* bv = (const float*)d_in[9];
  const float* Wo = (const float*)d_in[10]; const float* bo = (const float*)d_in[11];
  float* out = (float*)d_out;
  char* ws = (char*)d_ws;
  const size_t MB = 1024ull * 1024ull;
  u16* qbf = (u16*)(ws + 0 * MB);    // 16 MB each
  u16* kbf = (u16*)(ws + 16 * MB);
  u16* vbf = (u16*)(ws + 32 * MB);
  u16* Qp  = (u16*)(ws + 48 * MB);
  u16* Kp  = (u16*)(ws + 64 * MB);
  u16* Vtp = (u16*)(ws + 80 * MB);
  u16* Wqt = (u16*)(ws + 96 * MB);   // 2 MB each
  u16* Wkt = (u16*)(ws + 98 * MB);
  u16* Wvt = (u16*)(ws + 100 * MB);
  u16* Wot = (u16*)(ws + 102 * MB);
  u32* pmb = (u32*)(ws + 104 * MB);  // 2 MB
  u16* Oa  = qbf;  // qbf is dead after the Q projection; reuse for attention output

  const float QSCALE = 0.125f * L2E;  // fold score scale + log2(e) into Q projection

  cvt3_kernel<<<dim3(4096, 1, 3), 256, 0, stream>>>(q, k, v, qbf, kbf, vbf);
  wtrans_kernel<<<dim3(16, 16, 4), 256, 0, stream>>>(Wq, Wk, Wv, Wo, Wqt, Wkt, Wvt, Wot);
  packmask_kernel<<<dim3(65536), 256, 0, stream>>>(mask, pmb);
  gemm_kernel<0><<<dim3(256), 512, 0, stream>>>(qbf, Wqt, bq, Qp, QSCALE);
  gemm_kernel<0><<<dim3(256), 512, 0, stream>>>(kbf, Wkt, bk, Kp, 1.0f);
  gemm_kernel<2><<<dim3(256), 512, 0, stream>>>(vbf, Wvt, bv, Vtp, 1.0f);
  attn_kernel<<<dim3(512), 512, 0, stream>>>(Qp, Kp, Vtp, pmb, Oa);
  gemm_kernel<1><<<dim3(256), 512, 0, stream>>>(Oa, Wot, bo, out, 1.0f);
}

// Round 17
// 245.291 us; speedup vs baseline: 3.8468x; 3.8468x over previous
//
#include <hip/hip_runtime.h>
#include <stdint.h>

typedef unsigned short u16;
typedef uint32_t u32;
typedef unsigned long long u64;
typedef short bf16x8 __attribute__((ext_vector_type(8)));
typedef float f32x4 __attribute__((ext_vector_type(4)));
typedef float f32x16 __attribute__((ext_vector_type(16)));

#define MFMA16 __builtin_amdgcn_mfma_f32_16x16x32_bf16
#define MFMA32 __builtin_amdgcn_mfma_f32_32x32x16_bf16
#define L2E 1.44269504088896340736f

static __device__ __forceinline__ u16 f2bf(float f) {
  union { float f; u32 u; } v; v.f = f;
  u32 r = v.u + 0x7FFFu + ((v.u >> 16) & 1u);
  return (u16)(r >> 16);
}

// hardware packed f32x2 -> bf16x2 (RNE); no builtin on gfx950 (guide m240)
static __device__ __forceinline__ u32 cvtpk(float lo, float hi) {
  u32 r;
  asm("v_cvt_pk_bf16_f32 %0, %1, %2" : "=v"(r) : "v"(lo), "v"(hi));
  return r;
}

static __device__ __forceinline__ void glds16(const u16* g, u16* l) {
  __builtin_amdgcn_global_load_lds((const __attribute__((address_space(1))) void*)g,
                                   (__attribute__((address_space(3))) void*)l, 16, 0, 0);
}

// -------- convert 3 fp32 tensors (same size) to bf16, 8 elems/thread --------
__global__ __launch_bounds__(256) void cvt3_kernel(
    const float* __restrict__ s0, const float* __restrict__ s1, const float* __restrict__ s2,
    u16* __restrict__ d0, u16* __restrict__ d1, u16* __restrict__ d2) {
  const float* s = (blockIdx.z == 0) ? s0 : (blockIdx.z == 1) ? s1 : s2;
  u16* d = (blockIdx.z == 0) ? d0 : (blockIdx.z == 1) ? d1 : d2;
  size_t i = ((size_t)blockIdx.x * 256 + threadIdx.x) * 8;
  float4 a = *(const float4*)(s + i);
  float4 c = *(const float4*)(s + i + 4);
  bf16x8 o;
  o[0] = (short)f2bf(a.x); o[1] = (short)f2bf(a.y);
  o[2] = (short)f2bf(a.z); o[3] = (short)f2bf(a.w);
  o[4] = (short)f2bf(c.x); o[5] = (short)f2bf(c.y);
  o[6] = (short)f2bf(c.z); o[7] = (short)f2bf(c.w);
  *(bf16x8*)(d + i) = o;
}

// -------- transpose-convert the 4 weight matrices: Wt[n][k] = bf16(W[k][n]) --------
__global__ __launch_bounds__(256) void wtrans_kernel(
    const float* __restrict__ w0, const float* __restrict__ w1,
    const float* __restrict__ w2, const float* __restrict__ w3,
    u16* __restrict__ t0, u16* __restrict__ t1, u16* __restrict__ t2, u16* __restrict__ t3) {
  const float* w = (blockIdx.z == 0) ? w0 : (blockIdx.z == 1) ? w1 : (blockIdx.z == 2) ? w2 : w3;
  u16* t = (blockIdx.z == 0) ? t0 : (blockIdx.z == 1) ? t1 : (blockIdx.z == 2) ? t2 : t3;
  __shared__ float tile[64][65];
  const int bx = blockIdx.x, by = blockIdx.y;
#pragma unroll
  for (int i = 0; i < 16; ++i) {
    int idx = i * 256 + threadIdx.x;
    int r = idx >> 6, c = idx & 63;
    tile[r][c] = w[(size_t)(by * 64 + r) * 1024 + bx * 64 + c];
  }
  __syncthreads();
#pragma unroll
  for (int i = 0; i < 16; ++i) {
    int idx = i * 256 + threadIdx.x;
    int r = idx >> 6, c = idx & 63;
    t[(size_t)(bx * 64 + r) * 1024 + by * 64 + c] = f2bf(tile[c][r]);
  }
}

// -------- pack int32 mask (0/1) into bits: word w covers k = 32w..32w+31 --------
__global__ __launch_bounds__(256) void packmask_kernel(const int* __restrict__ m,
                                                       u32* __restrict__ pmo) {
  const size_t i = (size_t)blockIdx.x * 256 + threadIdx.x;
  const int lane = threadIdx.x & 63;
  unsigned long long b = __ballot(m[i] != 0);
  if (lane == 0) pmo[i >> 5] = (u32)b;
  else if (lane == 32) pmo[i >> 5] = (u32)(b >> 32);
}

// -------- bf16 GEMM: BM=256 BN=128 BK=64, 512 thr (8 waves 4Mx2N), 3-buffer --------
// counted-vmcnt (T4), XOR-swizzled LDS (T2), setprio (T5), T1 XCD block swizzle,
// phase-split K-step (T3): unchanged from round 14 (proven 29 -> 24.5 us).
template <int OM>
__global__ __launch_bounds__(512, 2) void gemm_kernel(
    const u16* __restrict__ A, const u16* __restrict__ Bt, const float* __restrict__ bias,
    void* __restrict__ Cout, float oscale) {
  constexpr int K = 1024, N = 1024;
  constexpr int NT = K / 64;  // 16 K-tiles
  __shared__ u16 As[3][256 * 64];  // 96 KB
  __shared__ u16 Bs[3][128 * 64];  // 48 KB
  const int tid = threadIdx.x;
  const int lane = tid & 63;
  const int wid = tid >> 6;       // 0..7
  const int l15 = lane & 15;
  const int lg = lane >> 4;
  const int orig = blockIdx.x;                     // 0..255
  const int wgid = (orig & 7) * 32 + (orig >> 3);  // XCD-contiguous remap
  const int row0 = (wgid >> 3) * 256;              // 32 row-panels
  const int col0 = (wgid & 7) * 128;               // 8 col-blocks
  const int wr = wid >> 1, wc = wid & 1;  // 4M x 2N wave grid
  const int swf = (l15 & 7) << 3;         // read-side XOR swizzle (u16 units)
  const f32x4 fzero = {0.f, 0.f, 0.f, 0.f};

  f32x4 acc[4][4];
#pragma unroll
  for (int m = 0; m < 4; ++m)
#pragma unroll
    for (int n = 0; n < 4; ++n) acc[m][n] = fzero;

  // A-loads i in [a0,a1), B-loads i in [b0,b1)
#define GSTAGE_PART(buf, k0, a0, a1, b0, b1)                                   \
  do {                                                                         \
    _Pragma("unroll") for (int i = (a0); i < (a1); ++i) {                      \
      int e = (i * 512 + tid) * 8;                                             \
      int r = e >> 6, c = e & 63;                                              \
      int cs = c ^ ((r & 7) << 3);                                             \
      glds16(A + (size_t)(row0 + r) * K + (k0) + cs, &As[buf][e]);             \
    }                                                                          \
    _Pragma("unroll") for (int i = (b0); i < (b1); ++i) {                      \
      int e = (i * 512 + tid) * 8;                                             \
      int r = e >> 6, c = e & 63;                                              \
      int cs = c ^ ((r & 7) << 3);                                             \
      glds16(Bt + (size_t)(col0 + r) * K + (k0) + cs, &Bs[buf][e]);            \
    }                                                                          \
  } while (0)

  GSTAGE_PART(0, 0, 0, 4, 0, 2);
  GSTAGE_PART(1, 64, 0, 4, 0, 2);
  asm volatile("s_waitcnt vmcnt(6)" ::: "memory");  // tile 0 landed
  __builtin_amdgcn_s_barrier();
  __builtin_amdgcn_sched_barrier(0);

  for (int t = 0; t < NT; ++t) {
    const int buf = t % 3;
    const int buf2 = (t + 2) % 3;
    const int k2 = (t + 2) * 64;
    const bool stg = (t + 2 < NT);

    // ---- phase 0: frags(ks=0) + first staging half ----
    {
      const int koff = 0 * 32 + lg * 8;
      bf16x8 af[4], bfr[4];
#pragma unroll
      for (int m = 0; m < 4; ++m)
        af[m] = *(const bf16x8*)(&As[buf][(wr * 64 + m * 16 + l15) * 64 + (koff ^ swf)]);
#pragma unroll
      for (int n = 0; n < 4; ++n)
        bfr[n] = *(const bf16x8*)(&Bs[buf][(wc * 64 + n * 16 + l15) * 64 + (koff ^ swf)]);
      if (stg) GSTAGE_PART(buf2, k2, 0, 2, 0, 1);
      __builtin_amdgcn_sched_barrier(0);
      __builtin_amdgcn_s_barrier();
      asm volatile("s_waitcnt lgkmcnt(0)" ::: "memory");
      __builtin_amdgcn_sched_barrier(0);
      __builtin_amdgcn_s_setprio(1);
#pragma unroll
      for (int m = 0; m < 4; ++m)
#pragma unroll
        for (int n = 0; n < 4; ++n)
          acc[m][n] = MFMA16(af[m], bfr[n], acc[m][n], 0, 0, 0);
      __builtin_amdgcn_s_setprio(0);
      __builtin_amdgcn_sched_barrier(0);
      __builtin_amdgcn_s_barrier();
    }

    // ---- phase 1: frags(ks=1) + second staging half ----
    {
      const int koff = 1 * 32 + lg * 8;
      bf16x8 af[4], bfr[4];
#pragma unroll
      for (int m = 0; m < 4; ++m)
        af[m] = *(const bf16x8*)(&As[buf][(wr * 64 + m * 16 + l15) * 64 + (koff ^ swf)]);
#pragma unroll
      for (int n = 0; n < 4; ++n)
        bfr[n] = *(const bf16x8*)(&Bs[buf][(wc * 64 + n * 16 + l15) * 64 + (koff ^ swf)]);
      if (stg) GSTAGE_PART(buf2, k2, 2, 4, 1, 2);
      __builtin_amdgcn_sched_barrier(0);
      __builtin_amdgcn_s_barrier();
      asm volatile("s_waitcnt lgkmcnt(0)" ::: "memory");
      __builtin_amdgcn_sched_barrier(0);
      __builtin_amdgcn_s_setprio(1);
#pragma unroll
      for (int m = 0; m < 4; ++m)
#pragma unroll
        for (int n = 0; n < 4; ++n)
          acc[m][n] = MFMA16(af[m], bfr[n], acc[m][n], 0, 0, 0);
      __builtin_amdgcn_s_setprio(0);
    }

    if (t + 1 < NT) {
      if (t + 2 < NT)
        asm volatile("s_waitcnt vmcnt(6)" ::: "memory");  // tile t+1 landed, t+2 in flight
      else
        asm volatile("s_waitcnt vmcnt(0)" ::: "memory");  // tail: last tile landed
      __builtin_amdgcn_s_barrier();
      __builtin_amdgcn_sched_barrier(0);
    }
  }
#undef GSTAGE_PART

#pragma unroll
  for (int n = 0; n < 4; ++n) {
    const int col = col0 + wc * 64 + n * 16 + l15;
    const float bv = bias[col];
#pragma unroll
    for (int m = 0; m < 4; ++m) {
#pragma unroll
      for (int r = 0; r < 4; ++r) {
        const int row = row0 + wr * 64 + m * 16 + lg * 4 + r;
        const float v = (acc[m][n][r] + bv) * oscale;
        if constexpr (OM == 0) {
          ((u16*)Cout)[(size_t)row * N + col] = f2bf(v);
        } else if constexpr (OM == 1) {
          ((float*)Cout)[(size_t)row * N + col] = v;
        } else {
          const int b_ = row >> 11, s_ = row & 2047, h_ = col >> 6, d_ = col & 63;
          ((u16*)Cout)[(size_t)((b_ * 16 + h_) * 64 + d_) * 2048 + s_] = f2bf(v);
        }
      }
    }
  }
}

// -------- flash attention: 32x32x16 MFMA, in-register P via permlane32_swap --------
// Round-14 proven config (256 thr, 4 waves, 2-buffer K/V, 4 blocks/CU) + T5:
// s_setprio(1) around the QK^T and PV MFMA clusters (m191: +4-7% on attn —
// attn blocks are independent, so waves sit at different phases and priority
// arbitration pays, unlike barrier-lockstep GEMM pre-split).
// NOTE (round-16 lesson): occupancy bounds must budget the UNIFIED VGPR+AGPR
// file — attn needs ~60 VGPR + 32 AGPR, so 8 waves/SIMD (64-reg cap) spills
// catastrophically. 4 blocks x 4 waves is the ceiling here.
__global__ __launch_bounds__(256, 4) void attn_kernel(
    const u16* __restrict__ Qb, const u16* __restrict__ Kb, const u16* __restrict__ Vt,
    const u32* __restrict__ pm, u16* __restrict__ Oa) {
  __shared__ u16 Ks[2][64 * 64];
  __shared__ u16 Vs[2][64 * 64];
  __shared__ uint4 mlut[16];  // 4 keep-bits -> 4 u32 AND-words
  const int tid = threadIdx.x;
  const int lane = tid & 63;
  const int wid = tid >> 6;
  const int c31 = lane & 31;
  const int hi = lane >> 5;
  const int orig = blockIdx.x;                    // 0..1023
  const int wgid = (orig & 7) * 128 + (orig >> 3);  // XCD-contiguous remap
  const int qt = wgid & 15;         // 16 q-tiles
  const int hh = (wgid >> 4) & 15;  // 16 heads
  const int bb = wgid >> 8;         // 4 batches
  const int qbase = qt * 128 + wid * 32;
  const int sw = (lane & 7) << 3;  // LDS read-side XOR swizzle (u16 units)

  if (tid < 16)
    mlut[tid] = make_uint4((u32) - (int)(tid & 1), (u32) - (int)((tid >> 1) & 1),
                           (u32) - (int)((tid >> 2) & 1), (u32) - (int)((tid >> 3) & 1));

  // Q B-fragments: col = q = qbase + c31, k = hi*8 + e, d = ds*16 + k
  const size_t qrow = (size_t)(bb * 2048 + qbase + c31);
  bf16x8 qf[4];
#pragma unroll
  for (int ds = 0; ds < 4; ++ds)
    qf[ds] = *(const bf16x8*)(Qb + qrow * 1024 + hh * 64 + ds * 16 + hi * 8);

  float lrun = 0.f;
  f32x16 oacc[2];
#pragma unroll
  for (int dn = 0; dn < 2; ++dn)
#pragma unroll
    for (int r = 0; r < 16; ++r) oacc[dn][r] = 0.f;

  const size_t kgbase = (size_t)(bb * 2048) * 1024 + hh * 64;
  const size_t vgbase = (size_t)((bb * 16 + hh) * 64) * 2048;

#define STAGE(buf, kbase)                                                              \
  do {                                                                                 \
    _Pragma("unroll") for (int i = 0; i < 2; ++i) {                                    \
      int r = ((i * 256 + tid) * 8) >> 6, c = ((i * 256 + tid) * 8) & 63;              \
      int cs = c ^ ((r & 7) << 3);                                                     \
      glds16(Kb + kgbase + (size_t)((kbase) + r) * 1024 + cs,                          \
             &Ks[buf][(i * 256 + wid * 64) * 8]);                                      \
      glds16(Vt + vgbase + (size_t)r * 2048 + (kbase) + cs,                            \
             &Vs[buf][(i * 256 + wid * 64) * 8]);                                      \
    }                                                                                  \
  } while (0)

  STAGE(0, 0);
  __syncthreads();  // buf0 staged (vmcnt0), mlut visible

  int cur = 0;
  for (int kt = 0; kt < 32; ++kt) {
    if (kt < 31) STAGE(cur ^ 1, (kt + 1) * 64);

    // both 32-key mask words for this tile (row = this lane's q)
    const u64 mw = *(const u64*)(pm + qrow * 64 + kt * 2);
    float ps = 0.f;

#pragma unroll
    for (int kb = 0; kb < 2; ++kb) {
      // QK^T: St[key = kb*32 + (r&3)+8*(r>>2)+4*hi][q = c31]
      f32x16 sacc;
#pragma unroll
      for (int r = 0; r < 16; ++r) sacc[r] = 0.f;
      __builtin_amdgcn_s_setprio(1);
#pragma unroll
      for (int ds = 0; ds < 4; ++ds) {
        bf16x8 kf = *(const bf16x8*)(&Ks[cur][(kb * 32 + c31) * 64 + ((ds * 16 + hi * 8) ^ sw)]);
        sacc = MFMA32(kf, qf[ds], sacc, 0, 0, 0);
      }
      __builtin_amdgcn_s_setprio(0);

      // exp + LUT mask + pack to bf16 pairs (in registers)
      const u32 mwk = (u32)(mw >> (kb * 32));
      u32 Ap[4], Bp[4];
#pragma unroll
      for (int q2 = 0; q2 < 4; ++q2) {
        const u32 kb4 = (mwk >> (q2 * 8 + hi * 4)) & 0xFu;
        const uint4 mm = mlut[kb4];
        const float p0 = __builtin_amdgcn_exp2f(sacc[4 * q2 + 0]);
        const float p1 = __builtin_amdgcn_exp2f(sacc[4 * q2 + 1]);
        const float p2 = __builtin_amdgcn_exp2f(sacc[4 * q2 + 2]);
        const float p3 = __builtin_amdgcn_exp2f(sacc[4 * q2 + 3]);
        const float f0 = __uint_as_float(__float_as_uint(p0) & mm.x);
        const float f1 = __uint_as_float(__float_as_uint(p1) & mm.y);
        const float f2 = __uint_as_float(__float_as_uint(p2) & mm.z);
        const float f3 = __uint_as_float(__float_as_uint(p3) & mm.w);
        ps += (f0 + f1) + (f2 + f3);
        Ap[q2] = cvtpk(f0, f1);
        Bp[q2] = cvtpk(f2, f3);
      }

      // redistribute across hi-halves: B-frag regs r0,r2 from A-pair swap, r1,r3 from B-pair
      asm("v_permlane32_swap_b32 %0, %1" : "+v"(Ap[0]), "+v"(Ap[1]));
      asm("v_permlane32_swap_b32 %0, %1" : "+v"(Bp[0]), "+v"(Bp[1]));
      asm("v_permlane32_swap_b32 %0, %1" : "+v"(Ap[2]), "+v"(Ap[3]));
      asm("v_permlane32_swap_b32 %0, %1" : "+v"(Bp[2]), "+v"(Bp[3]));

      // PV: O^T[d][q] += V^T[d][key] * P[key][q], 2 key-steps of 16 per kb
      __builtin_amdgcn_s_setprio(1);
#pragma unroll
      for (int t = 0; t < 2; ++t) {
        uint4 fr;
        fr.x = Ap[2 * t]; fr.y = Bp[2 * t]; fr.z = Ap[2 * t + 1]; fr.w = Bp[2 * t + 1];
        const bf16x8 pf = *(const bf16x8*)&fr;
        const int koff = (kb * 2 + t) * 16 + hi * 8;
#pragma unroll
        for (int dn = 0; dn < 2; ++dn) {
          bf16x8 vf = *(const bf16x8*)(&Vs[cur][(dn * 32 + c31) * 64 + (koff ^ sw)]);
          oacc[dn] = MFMA32(vf, pf, oacc[dn], 0, 0, 0);
        }
      }
      __builtin_amdgcn_s_setprio(0);
    }

    ps += __shfl_xor(ps, 32);
    lrun += ps;

    __syncthreads();  // vmcnt(0): next tile staged; lgkmcnt(0): buf[cur] reads done
    cur ^= 1;
  }
#undef STAGE

  // epilogue: O[q][d], lane owns q = qbase + c31; d = dn*32 + q2*8 + hi*4 + {0..3}
  const float inv = 1.0f / lrun;
  u16* orow = Oa + qrow * 1024 + hh * 64;
#pragma unroll
  for (int dn = 0; dn < 2; ++dn) {
#pragma unroll
    for (int q2 = 0; q2 < 4; ++q2) {
      uint2 w;
      w.x = cvtpk(oacc[dn][4 * q2 + 0] * inv, oacc[dn][4 * q2 + 1] * inv);
      w.y = cvtpk(oacc[dn][4 * q2 + 2] * inv, oacc[dn][4 * q2 + 3] * inv);
      *(uint2*)(orow + dn * 32 + q2 * 8 + hi * 4) = w;
    }
  }
}

extern "C" void kernel_launch(void* const* d_in, const int* in_sizes, int n_in,
                              void* d_out, int out_size, void* d_ws, size_t ws_size,
                              hipStream_t stream) {
  const float* q = (const float*)d_in[0];
  const float* k = (const float*)d_in[1];
  const float* v = (const float*)d_in[2];
  const int* mask = (const int*)d_in[3];
  const float* Wq = (const float*)d_in[4]; const float* bq = (const float*)d_in[5];
  const float* Wk = (const float*)d_in[6]; const float* bk = (const float*)d_in[7];
  const float* Wv = (const float*)d_in[8]; const float* bv = (const float*)d_in[9];
  const float* Wo = (const float*)d_in[10]; const float* bo = (const float*)d_in[11];
  float* out = (float*)d_out;
  char* ws = (char*)d_ws;
  const size_t MB = 1024ull * 1024ull;
  u16* qbf = (u16*)(ws + 0 * MB);    // 16 MB each
  u16* kbf = (u16*)(ws + 16 * MB);
  u16* vbf = (u16*)(ws + 32 * MB);
  u16* Qp  = (u16*)(ws + 48 * MB);
  u16* Kp  = (u16*)(ws + 64 * MB);
  u16* Vtp = (u16*)(ws + 80 * MB);
  u16* Wqt = (u16*)(ws + 96 * MB);   // 2 MB each
  u16* Wkt = (u16*)(ws + 98 * MB);
  u16* Wvt = (u16*)(ws + 100 * MB);
  u16* Wot = (u16*)(ws + 102 * MB);
  u32* pmb = (u32*)(ws + 104 * MB);  // 2 MB
  u16* Oa  = qbf;  // qbf is dead after the Q projection; reuse for attention output

  const float QSCALE = 0.125f * L2E;  // fold score scale + log2(e) into Q projection

  cvt3_kernel<<<dim3(4096, 1, 3), 256, 0, stream>>>(q, k, v, qbf, kbf, vbf);
  wtrans_kernel<<<dim3(16, 16, 4), 256, 0, stream>>>(Wq, Wk, Wv, Wo, Wqt, Wkt, Wvt, Wot);
  packmask_kernel<<<dim3(65536), 256, 0, stream>>>(mask, pmb);
  gemm_kernel<0><<<dim3(256), 512, 0, stream>>>(qbf, Wqt, bq, Qp, QSCALE);
  gemm_kernel<0><<<dim3(256), 512, 0, stream>>>(kbf, Wkt, bk, Kp, 1.0f);
  gemm_kernel<2><<<dim3(256), 512, 0, stream>>>(vbf, Wvt, bv, Vtp, 1.0f);
  attn_kernel<<<dim3(1024), 256, 0, stream>>>(Qp, Kp, Vtp, pmb, Oa);
  gemm_kernel<1><<<dim3(256), 512, 0, stream>>>(Oa, Wot, bo, out, 1.0f);
}